// Round 21
// baseline (309.747 us; speedup 1.0000x reference)
//
#include <hip/hip_runtime.h>
#include <cmath>

// B=2, S=4096, DM=768, H=12, FF=3072, BLOCK=64, NB=64, R=3, d=64
// Round 21: round-19 design; arg-count fix on W2 call (13 args, verified).
// GEMMs: 128x64 tile, 3-buffer 2-deep prefetch, counted vmcnt(6), T2 swizzle,
// 72KB LDS -> 2 blocks/CU. attn5/combine/LN/prep unchanged from round 17.

typedef unsigned short bf;
typedef __attribute__((ext_vector_type(8))) short bf16x8;
typedef __attribute__((ext_vector_type(4))) float f32x4;

__device__ __forceinline__ float bf2f(bf u) { return __uint_as_float(((unsigned)u) << 16); }
__device__ __forceinline__ bf f2bf(float f) {
  unsigned x = __float_as_uint(f);
  x += 0x7FFFu + ((x >> 16) & 1u);   // round-to-nearest-even
  return (bf)(x >> 16);
}

// async global->LDS, 16B per lane; LDS dest = wave-uniform base + lane*16
__device__ __forceinline__ void gload16(const bf* g, char* lds) {
  __builtin_amdgcn_global_load_lds(
      (const __attribute__((address_space(1))) void*)g,
      (__attribute__((address_space(3))) void*)lds, 16, 0, 0);
}

// ---- x f32 -> bf16 (8/thread) ----
__global__ __launch_bounds__(256) void cvt_x_k(const float* __restrict__ X,
                                               bf* __restrict__ xb)
{
  size_t i = ((size_t)blockIdx.x * 256 + threadIdx.x) * 8;
  float4 f0 = *(const float4*)&X[i];
  float4 f1 = *(const float4*)&X[i + 4];
  *(ushort4*)&xb[i]     = make_ushort4(f2bf(f0.x), f2bf(f0.y), f2bf(f0.z), f2bf(f0.w));
  *(ushort4*)&xb[i + 4] = make_ushort4(f2bf(f1.x), f2bf(f1.y), f2bf(f1.z), f2bf(f1.w));
}

// ---- W [K][N] f32 -> Wt [N][K] bf16, 64x64 LDS tile ----
__global__ __launch_bounds__(256) void tconv_k(const float* __restrict__ W,
                                               bf* __restrict__ Wt, int K, int N)
{
  __shared__ float tile[64][65];
  const int t = threadIdx.x;
  const int bn = blockIdx.x * 64, bk = blockIdx.y * 64;
  const int r = t >> 2, c0 = (t & 3) * 16;
  #pragma unroll
  for (int i = 0; i < 4; ++i) {
    float4 f = *(const float4*)&W[(size_t)(bk + r) * N + bn + c0 + i * 4];
    tile[r][c0 + i*4 + 0] = f.x; tile[r][c0 + i*4 + 1] = f.y;
    tile[r][c0 + i*4 + 2] = f.z; tile[r][c0 + i*4 + 3] = f.w;
  }
  __syncthreads();
  #pragma unroll
  for (int i = 0; i < 4; ++i) {
    int c = c0 + i * 4;
    ushort4 u = make_ushort4(f2bf(tile[c + 0][r]), f2bf(tile[c + 1][r]),
                             f2bf(tile[c + 2][r]), f2bf(tile[c + 3][r]));
    *(ushort4*)&Wt[(size_t)(bn + r) * K + bk + c] = u;
  }
}

// ---- 128x64-tile GEMM, 3-buffer 2-deep prefetch, counted vmcnt(6), T2 swizzle.
// A[M][K] bf16, Bt[N][ldbt] bf16 (row = out col). QKVMODE routes 768-segments.
template <int QKVMODE, typename TC>
__global__ __launch_bounds__(256) void gl3_gemm_k(
    const bf* __restrict__ A, const bf* __restrict__ Bt,
    const float* __restrict__ b0p, const float* __restrict__ b1p,
    const float* __restrict__ b2p,
    TC* __restrict__ C0, bf* __restrict__ C1, bf* __restrict__ C2,
    int M, int N, int K, int ldbt, int ep)
{
  constexpr int BUF = 24576;          // A 16K + B 8K
  __shared__ char smem[3 * BUF];      // 72 KB -> 2 blocks/CU
  const int t = threadIdx.x;
  const int bm = blockIdx.y * 128, bn = blockIdx.x * 64;
  const int lane = t & 63, wid = t >> 6;
  const int wm = wid >> 1, wn = wid & 1;
  const int fr = lane & 15, fq = lane >> 4;

  f32x4 acc[4][2];
  #pragma unroll
  for (int i = 0; i < 4; ++i)
    #pragma unroll
    for (int j = 0; j < 2; ++j) acc[i][j] = (f32x4){0.f, 0.f, 0.f, 0.f};

  // 6 gloads/thread/tile: A rows 0-127 (4 chunks), B cols 0-63 (2 chunks).
  auto STAGE = [&](int p, int k0) {
    char* sA = smem + p * BUF;
    char* sB = sA + 16384;
    #pragma unroll
    for (int c = 0; c < 4; ++c) {
      int idx = c * 256 + t;
      int row = idx >> 3, ks = idx & 7;
      gload16(A + (size_t)(bm + row) * K + k0 + ((ks ^ (row & 7)) << 3),
              sA + (c * 256 + wid * 64) * 16);
    }
    #pragma unroll
    for (int c = 0; c < 2; ++c) {
      int idx = c * 256 + t;
      int row = idx >> 3, ks = idx & 7;
      gload16(Bt + (size_t)(bn + row) * ldbt + k0 + ((ks ^ (row & 7)) << 3),
              sB + (c * 256 + wid * 64) * 16);
    }
  };

  const int T = K >> 6;
  STAGE(0, 0);
  STAGE(1, 64);
  asm volatile("s_waitcnt vmcnt(6)" ::: "memory");   // tile 0 landed
  __builtin_amdgcn_s_barrier();
  __builtin_amdgcn_sched_barrier(0);
  for (int tt = 0; tt < T; ++tt) {
    if (tt + 2 < T) STAGE((tt + 2) % 3, (tt + 2) * 64);
    __builtin_amdgcn_sched_barrier(0);
    char* sA = smem + (tt % 3) * BUF;
    char* sB = sA + 16384;
    __builtin_amdgcn_s_setprio(1);
    #pragma unroll
    for (int kk = 0; kk < 2; ++kk) {
      const int kb = kk * 64 + fq * 16;
      bf16x8 a[4], b[2];
      #pragma unroll
      for (int i = 0; i < 4; ++i) {
        int row = wm * 64 + i * 16 + fr;
        a[i] = *(const bf16x8*)(sA + row * 128 + (kb ^ ((row & 7) << 4)));
      }
      #pragma unroll
      for (int j = 0; j < 2; ++j) {
        int col = wn * 32 + j * 16 + fr;
        b[j] = *(const bf16x8*)(sB + col * 128 + (kb ^ ((col & 7) << 4)));
      }
      #pragma unroll
      for (int i = 0; i < 4; ++i)
        #pragma unroll
        for (int j = 0; j < 2; ++j)
          acc[i][j] = __builtin_amdgcn_mfma_f32_16x16x32_bf16(a[i], b[j], acc[i][j], 0, 0, 0);
    }
    __builtin_amdgcn_s_setprio(0);
    __builtin_amdgcn_sched_barrier(0);
    // counted wait: only tile tt+1's loads must land; tt+2's stay in flight
    if (tt + 2 < T) { asm volatile("s_waitcnt vmcnt(6)" ::: "memory"); }
    else            { asm volatile("s_waitcnt vmcnt(0)" ::: "memory"); }
    __builtin_amdgcn_s_barrier();
    __builtin_amdgcn_sched_barrier(0);
  }
  // ---- epilogue ----
  if constexpr (QKVMODE) {
    const int seg = bn / 768;
    const int cb  = bn - seg * 768;
    bf* dst = (seg == 0) ? (bf*)C0 : ((seg == 1) ? C1 : C2);
    const float* bias = (seg == 0) ? b0p : ((seg == 1) ? b1p : b2p);
    #pragma unroll
    for (int j = 0; j < 2; ++j) {
      int col = cb + wn * 32 + j * 16 + fr;
      float bias_v = bias[col];
      #pragma unroll
      for (int i = 0; i < 4; ++i) {
        int row0 = bm + wm * 64 + i * 16 + fq * 4;
        #pragma unroll
        for (int r = 0; r < 4; ++r)
          dst[(size_t)(row0 + r) * 768 + col] = f2bf(acc[i][j][r] + bias_v);
      }
    }
  } else {
    #pragma unroll
    for (int j = 0; j < 2; ++j) {
      int col = bn + wn * 32 + j * 16 + fr;
      float bias_v = b0p ? b0p[col] : 0.f;
      #pragma unroll
      for (int i = 0; i < 4; ++i) {
        int row0 = bm + wm * 64 + i * 16 + fq * 4;
        #pragma unroll
        for (int r = 0; r < 4; ++r) {
          float v = acc[i][j][r] + bias_v;
          if (ep == 1) v = 0.5f * v * (1.0f + erff(v * 0.70710678118654752f));
          if constexpr (sizeof(TC) == 2) C0[(size_t)(row0 + r) * N + col] = f2bf(v);
          else                           C0[(size_t)(row0 + r) * N + col] = v;
        }
      }
    }
  }
}

// stage one prefetched K/V block into LDS buffers
__device__ __forceinline__ void stage_kv(char* bK, char* bVT,
    int kkey, int kd0, int vkey, int w,
    uint4 k0, uint4 k1, uint4 v0, uint4 v1)
{
  const int sw = (kkey & 7) << 4;
  *(uint4*)(bK + kkey * 128 + ((2 * kd0) ^ sw))      = k0;
  *(uint4*)(bK + kkey * 128 + ((2 * kd0 + 16) ^ sw)) = k1;
  union { uint4 q; unsigned short s[8]; } a, c;
  a.q = v0; c.q = v1;
  #pragma unroll
  for (int i = 0; i < 8; ++i) {
    int d = w * 16 + i;
    *(unsigned short*)(bVT + d * 128 + ((2 * vkey) ^ ((d & 7) << 4))) = a.s[i];
  }
  #pragma unroll
  for (int i = 0; i < 8; ++i) {
    int d = w * 16 + 8 + i;
    *(unsigned short*)(bVT + d * 128 + ((2 * vkey) ^ ((d & 7) << 4))) = c.s[i];
  }
}

// ---------------- BigBird attention v5 (unchanged) ----------------
__global__ __launch_bounds__(256) void attn5_kernel(
    const bf* __restrict__ Q, const bf* __restrict__ K,
    const bf* __restrict__ V, const int* __restrict__ rnd,
    float* __restrict__ ctx, float* __restrict__ part, int nseg)
{
  __shared__ char sQP[8192];
  __shared__ char sKV[2][16384];
  __shared__ int klist[8];
  const int t = threadIdx.x;
  const int lane = t & 63, w = t >> 6;
  const int fr = lane & 15, fq = lane >> 4;
  const int wg = blockIdx.x;
  const int nheavy = 48 * nseg;
  const bool heavy = wg < nheavy;
  int b, h, n, nkb, seg = 0, hidx = 0, segBase = 0;
  if (heavy) {
    hidx = wg / nseg; seg = wg - hidx * nseg;
    n = (hidx & 1) ? 63 : 0;
    int bh = hidx >> 1; h = bh % 12; b = bh / 12;
    nkb = 64 / nseg; segBase = seg * nkb;
  } else {
    int idx = wg - nheavy;
    n = 1 + (idx % 62);
    int bh = idx / 62; h = bh % 12; b = bh / 12;
    nkb = (n == 1 || n == 62) ? 7 : 8;
    if (t == 0) {
      int cnt = 0;
      if (n == 1)       { klist[0]=0; klist[1]=1;  klist[2]=2;  klist[3]=63; cnt=4; }
      else if (n == 62) { klist[0]=0; klist[1]=61; klist[2]=62; klist[3]=63; cnt=4; }
      else              { klist[0]=0; klist[1]=n-1; klist[2]=n; klist[3]=n+1; cnt=4; }
      for (int j = 0; j < 3; ++j) klist[cnt++] = rnd[(h * 62 + (n - 1)) * 3 + j];
      if (n != 1 && n != 62) klist[cnt++] = 63;
    }
  }
  const size_t qbase = ((size_t)b * 4096 + (size_t)n * 64) * 768 + h * 64;

  {
    int row = t >> 2, d0 = (t & 3) * 16;
    const bf* qp = &Q[qbase + (size_t)row * 768 + d0];
    #pragma unroll
    for (int i = 0; i < 2; ++i) {
      int off = row * 128 + ((2 * (d0 + 8 * i)) ^ ((row & 7) << 4));
      *(uint4*)(sQP + off) = *(const uint4*)(qp + 8 * i);
    }
  }
  __syncthreads();
  bf16x8 qf[2];
  {
    int row = w * 16 + fr;
    qf[0] = *(const bf16x8*)(sQP + row * 128 + ((2 * (fq * 8))      ^ ((row & 7) << 4)));
    qf[1] = *(const bf16x8*)(sQP + row * 128 + ((2 * (32 + fq * 8)) ^ ((row & 7) << 4)));
  }

  const int kkey = t >> 2, kd0 = (t & 3) * 16;
  const int vkey = lane;

  uint4 pk0, pk1, pv0, pv1;
  {
    int kb = heavy ? segBase : klist[0];
    size_t kbase = ((size_t)b * 4096 + (size_t)kb * 64) * 768 + h * 64;
    const bf* kp = &K[kbase + (size_t)kkey * 768 + kd0];
    pk0 = *(const uint4*)kp;  pk1 = *(const uint4*)(kp + 8);
    const bf* vp = &V[kbase + (size_t)vkey * 768 + w * 16];
    pv0 = *(const uint4*)vp;  pv1 = *(const uint4*)(vp + 8);
  }
  stage_kv(sKV[0], sKV[0] + 8192, kkey, kd0, vkey, w, pk0, pk1, pv0, pv1);

  float m_r[4] = {-1e30f, -1e30f, -1e30f, -1e30f};
  float l_r[4] = {0.f, 0.f, 0.f, 0.f};
  f32x4 acc_o[4];
  #pragma unroll
  for (int j = 0; j < 4; ++j) acc_o[j] = (f32x4){0.f, 0.f, 0.f, 0.f};

  for (int ib = 0; ib < nkb; ++ib) {
    char* bK  = sKV[ib & 1];
    char* bVT = bK + 8192;
    const bool pfv = (ib + 1 < nkb);
    if (pfv) {
      int kb = heavy ? (segBase + ib + 1) : klist[ib + 1];
      size_t kbase = ((size_t)b * 4096 + (size_t)kb * 64) * 768 + h * 64;
      const bf* kp = &K[kbase + (size_t)kkey * 768 + kd0];
      pk0 = *(const uint4*)kp;  pk1 = *(const uint4*)(kp + 8);
      const bf* vp = &V[kbase + (size_t)vkey * 768 + w * 16];
      pv0 = *(const uint4*)vp;  pv1 = *(const uint4*)(vp + 8);
    }
    __syncthreads();
    f32x4 s4[4];
    #pragma unroll
    for (int j = 0; j < 4; ++j) s4[j] = (f32x4){0.f, 0.f, 0.f, 0.f};
    __builtin_amdgcn_s_setprio(1);
    #pragma unroll
    for (int kk = 0; kk < 2; ++kk) {
      #pragma unroll
      for (int j = 0; j < 4; ++j) {
        int key = j * 16 + fr;
        bf16x8 kf = *(const bf16x8*)(bK + key * 128 + ((2 * (kk * 32 + fq * 8)) ^ ((key & 7) << 4)));
        s4[j] = __builtin_amdgcn_mfma_f32_16x16x32_bf16(qf[kk], kf, s4[j], 0, 0, 0);
      }
    }
    __builtin_amdgcn_s_setprio(0);
    #pragma unroll
    for (int j = 0; j < 4; ++j) s4[j] *= 0.125f;
    float c_r[4];
    #pragma unroll
    for (int r = 0; r < 4; ++r) {
      float mx = fmaxf(fmaxf(s4[0][r], s4[1][r]), fmaxf(s4[2][r], s4[3][r]));
      #pragma unroll
      for (int m = 1; m < 16; m <<= 1) mx = fmaxf(mx, __shfl_xor(mx, m, 64));
      float mn = fmaxf(mx, m_r[r]);
      float c  = __expf(m_r[r] - mn);
      float p0 = __expf(s4[0][r] - mn), p1 = __expf(s4[1][r] - mn);
      float p2 = __expf(s4[2][r] - mn), p3 = __expf(s4[3][r] - mn);
      s4[0][r] = p0; s4[1][r] = p1; s4[2][r] = p2; s4[3][r] = p3;
      float sum = p0 + p1 + p2 + p3;
      #pragma unroll
      for (int m = 1; m < 16; m <<= 1) sum += __shfl_xor(sum, m, 64);
      l_r[r] = l_r[r] * c + sum;
      m_r[r] = mn;
      c_r[r] = c;
    }
    #pragma unroll
    for (int j = 0; j < 4; ++j)
      #pragma unroll
      for (int r = 0; r < 4; ++r) acc_o[j][r] *= c_r[r];
    #pragma unroll
    for (int r = 0; r < 4; ++r) {
      int prow = w * 16 + fq * 4 + r;
      int rs = prow * 128, sw = (prow & 7) << 4;
      #pragma unroll
      for (int j = 0; j < 4; ++j)
        *(unsigned short*)(sQP + rs + ((2 * (j * 16 + fr)) ^ sw)) = f2bf(s4[j][r]);
    }
    if (pfv)
      stage_kv(sKV[(ib & 1) ^ 1], sKV[(ib & 1) ^ 1] + 8192, kkey, kd0, vkey, w,
               pk0, pk1, pv0, pv1);
    __builtin_amdgcn_s_setprio(1);
    #pragma unroll
    for (int kk = 0; kk < 2; ++kk) {
      int prow = w * 16 + fr;
      bf16x8 pf8 = *(const bf16x8*)(sQP + prow * 128 + ((2 * (kk * 32 + fq * 8)) ^ ((prow & 7) << 4)));
      #pragma unroll
      for (int j = 0; j < 4; ++j) {
        int col = j * 16 + fr;
        bf16x8 vf = *(const bf16x8*)(bVT + col * 128 + ((2 * (kk * 32 + fq * 8)) ^ ((col & 7) << 4)));
        acc_o[j] = __builtin_amdgcn_mfma_f32_16x16x32_bf16(pf8, vf, acc_o[j], 0, 0, 0);
      }
    }
    __builtin_amdgcn_s_setprio(0);
  }
  if (heavy && nseg > 1) {
    float* pb = part + ((size_t)hidx * nseg + seg) * 4224;
    int row0 = w * 16 + fq * 4;
    #pragma unroll
    for (int r = 0; r < 4; ++r) {
      int row = row0 + r;
      if (fr == 0) { pb[4096 + row] = m_r[r]; pb[4160 + row] = l_r[r]; }
      #pragma unroll
      for (int j = 0; j < 4; ++j)
        pb[row * 64 + j * 16 + fr] = acc_o[j][r];
    }
  } else {
    int row0 = w * 16 + fq * 4;
    #pragma unroll
    for (int r = 0; r < 4; ++r) {
      float inv = 1.f / l_r[r];
      size_t rowoff = qbase + (size_t)(row0 + r) * 768;
      #pragma unroll
      for (int j = 0; j < 4; ++j)
        ctx[rowoff + j * 16 + fr] = acc_o[j][r] * inv;
    }
  }
}

// ---- combine partials for heavy blocks (nseg=8) ----
__global__ __launch_bounds__(256) void attn_combine_k(
    const float* __restrict__ part, float* __restrict__ ctx)
{
  const int hidx = blockIdx.x;
  const int t = threadIdx.x;
  const int n = (hidx & 1) ? 63 : 0;
  const int bh = hidx >> 1;
  const int h = bh % 12, b = bh / 12;
  const size_t qbase = ((size_t)b * 4096 + (size_t)n * 64) * 768 + h * 64;
  const int r = t >> 2, d0 = (t & 3) * 16;
  const float* pb = part + (size_t)hidx * 8 * 4224;
  float mi[8], li[8], m = -1e30f;
  #pragma unroll
  for (int i = 0; i < 8; ++i) {
    mi[i] = pb[i * 4224 + 4096 + r];
    li[i] = pb[i * 4224 + 4160 + r];
    m = fmaxf(m, mi[i]);
  }
  float w8[8], L = 0.f;
  #pragma unroll
  for (int i = 0; i < 8; ++i) { w8[i] = __expf(mi[i] - m); L += li[i] * w8[i]; }
  float inv = 1.f / L;
  #pragma unroll
  for (int dd = 0; dd < 4; ++dd) {
    int d = d0 + dd * 4;
    float4 o = {0.f, 0.f, 0.f, 0.f};
    #pragma unroll
    for (int i = 0; i < 8; ++i) {
      float4 p = *(const float4*)&pb[i * 4224 + r * 64 + d];
      o.x = fmaf(w8[i], p.x, o.x); o.y = fmaf(w8[i], p.y, o.y);
      o.z = fmaf(w8[i], p.z, o.z); o.w = fmaf(w8[i], p.w, o.w);
    }
    o.x *= inv; o.y *= inv; o.z *= inv; o.w *= inv;
    *(float4*)&ctx[qbase + (size_t)r * 768 + d] = o;
  }
}

// ---------------- LayerNorm(a + res) * g + b ----------------
template <typename TR, typename TO>
__global__ __launch_bounds__(256) void ln_kernel(
    const float* __restrict__ a, const TR* __restrict__ res,
    const float* __restrict__ g, const float* __restrict__ bb,
    TO* __restrict__ out)
{
  const int row = blockIdx.x, t = threadIdx.x;
  __shared__ float buf[768];
  __shared__ float rs[4], rss[4];
  const size_t base = (size_t)row * 768;
  float s = 0.f, ss = 0.f;
  for (int c = t; c < 768; c += 256) {
    float rv;
    if constexpr (sizeof(TR) == 2) rv = bf2f(res[base + c]);
    else                           rv = res[base + c];
    float v = a[base + c] + rv;
    buf[c] = v;
    s += v;
    ss = fmaf(v, v, ss);
  }
  #pragma unroll
  for (int off = 32; off > 0; off >>= 1) {
    s  += __shfl_down(s, off, 64);
    ss += __shfl_down(ss, off, 64);
  }
  if ((t & 63) == 0) { rs[t >> 6] = s; rss[t >> 6] = ss; }
  __syncthreads();
  float S  = rs[0] + rs[1] + rs[2] + rs[3];
  float SS = rss[0] + rss[1] + rss[2] + rss[3];
  float mu  = S * (1.f / 768.f);
  float var = SS * (1.f / 768.f) - mu * mu;
  float inv = rsqrtf(var + 1e-5f);
  for (int c = t; c < 768; c += 256) {
    float v = (buf[c] - mu) * inv * g[c] + bb[c];
    if constexpr (sizeof(TO) == 2) out[base + c] = f2bf(v);
    else                           out[base + c] = v;
  }
}

extern "C" void kernel_launch(void* const* d_in, const int* in_sizes, int n_in,
                              void* d_out, int out_size, void* d_ws, size_t ws_size,
                              hipStream_t stream)
{
  const float* x   = (const float*)d_in[0];
  const int*   rnd = (const int*)d_in[1];
  const float* Wq  = (const float*)d_in[2];
  const float* bq  = (const float*)d_in[3];
  const float* Wk  = (const float*)d_in[4];
  const float* bk  = (const float*)d_in[5];
  const float* Wv  = (const float*)d_in[6];
  const float* bv  = (const float*)d_in[7];
  const float* g1  = (const float*)d_in[8];
  const float* be1 = (const float*)d_in[9];
  const float* W1  = (const float*)d_in[10];
  const float* b1  = (const float*)d_in[11];
  const float* W2  = (const float*)d_in[12];
  const float* b2  = (const float*)d_in[13];
  const float* g2  = (const float*)d_in[14];
  const float* be2 = (const float*)d_in[15];
  float* out = (float*)d_out;

  char* W = (char*)d_ws;
  bf* w1t   = (bf*)(W);                 // [3072][768]
  bf* w2t   = (bf*)(W + 4718592);       // [768][3072]
  bf* Kb    = (bf*)(W + 9437184);       // [8192][768], h1 later
  bf* wqkv  = (bf*)(W + 22020096);      // [2304][768]
  bf* xb    = (bf*)(W + 25559040);      // [8192][768]
  bf* Qb    = (bf*)(W + 38141952);      // [8192][768]
  bf* Vb    = (bf*)(W + 50724864);      // [8192][768]
  float* part = (float*)(W + 63307776); // 48*8*4224 f32
  bf* f1    = (bf*)(W + 22020096);      // [8192][3072], overlays dead buffers
  bf* h1    = Kb;
  float* ctx = out;
  float* f2  = out;

  dim3 blk(256);
  cvt_x_k<<<dim3(3072), blk, 0, stream>>>(x, xb);
  tconv_k<<<dim3(12, 12), blk, 0, stream>>>(Wq, wqkv,               768, 768);
  tconv_k<<<dim3(12, 12), blk, 0, stream>>>(Wk, wqkv + 589824,      768, 768);
  tconv_k<<<dim3(12, 12), blk, 0, stream>>>(Wv, wqkv + 2 * 589824,  768, 768);
  tconv_k<<<dim3(48, 12), blk, 0, stream>>>(W1, w1t,  768, 3072);
  tconv_k<<<dim3(12, 48), blk, 0, stream>>>(W2, w2t, 3072,  768);
  // QKV: N=2304 over [Wq|Wk|Wv]^T, segment-routed epilogue
  gl3_gemm_k<1, bf><<<dim3(36, 64), blk, 0, stream>>>(
      xb, wqkv, bq, bk, bv, Qb, Kb, Vb, 8192, 2304, 768, 768, 0);
  attn5_kernel<<<dim3(48 * 8 + 2 * 12 * 62), blk, 0, stream>>>(
      Qb, Kb, Vb, rnd, ctx, part, 8);
  attn_combine_k<<<dim3(48), blk, 0, stream>>>(part, ctx);
  ln_kernel<float, bf><<<dim3(8192), blk, 0, stream>>>(ctx, x, g1, be1, h1);
  // W1: GELU epilogue, bf16 out
  gl3_gemm_k<0, bf><<<dim3(48, 64), blk, 0, stream>>>(
      h1, w1t, b1, nullptr, nullptr, f1, nullptr, nullptr, 8192, 3072, 768, 768, 1);
  // W2: f32 out into d_out (13 args: A,Bt,b0p,b1p,b2p,C0,C1,C2,M,N,K,ldbt,ep)
  gl3_gemm_k<0, float><<<dim3(12, 64), blk, 0, stream>>>(
      f1, w2t, b2, nullptr, nullptr, f2, nullptr, nullptr, 8192, 768, 3072, 3072, 0);
  ln_kernel<bf, float><<<dim3(8192), blk, 0, stream>>>(f2, h1, g2, be2, out);
}

// Round 22
// 280.328 us; speedup vs baseline: 1.1049x; 1.1049x over previous
//
#include <hip/hip_runtime.h>
#include <cmath>

// B=2, S=4096, DM=768, H=12, FF=3072, BLOCK=64, NB=64, R=3, d=64
// Round 22: consolidate to round-17 proven config (283.6 us) after r18/r21
// schedule experiments regressed. Only change: 3x QKV weight transposes merged
// into one 3-slice launch. GEMMs: 128xBN 2-phase dbuf + T2 source-swizzle.

typedef unsigned short bf;
typedef __attribute__((ext_vector_type(8))) short bf16x8;
typedef __attribute__((ext_vector_type(4))) float f32x4;

__device__ __forceinline__ float bf2f(bf u) { return __uint_as_float(((unsigned)u) << 16); }
__device__ __forceinline__ bf f2bf(float f) {
  unsigned x = __float_as_uint(f);
  x += 0x7FFFu + ((x >> 16) & 1u);   // round-to-nearest-even
  return (bf)(x >> 16);
}

// async global->LDS, 16B per lane; LDS dest = wave-uniform base + lane*16
__device__ __forceinline__ void gload16(const bf* g, char* lds) {
  __builtin_amdgcn_global_load_lds(
      (const __attribute__((address_space(1))) void*)g,
      (__attribute__((address_space(3))) void*)lds, 16, 0, 0);
}

// ---- x f32 -> bf16 (8/thread) ----
__global__ __launch_bounds__(256) void cvt_x_k(const float* __restrict__ X,
                                               bf* __restrict__ xb)
{
  size_t i = ((size_t)blockIdx.x * 256 + threadIdx.x) * 8;
  float4 f0 = *(const float4*)&X[i];
  float4 f1 = *(const float4*)&X[i + 4];
  *(ushort4*)&xb[i]     = make_ushort4(f2bf(f0.x), f2bf(f0.y), f2bf(f0.z), f2bf(f0.w));
  *(ushort4*)&xb[i + 4] = make_ushort4(f2bf(f1.x), f2bf(f1.y), f2bf(f1.z), f2bf(f1.w));
}

// ---- W [K][N] f32 -> Wt [N][K] bf16, 64x64 LDS tile ----
__global__ __launch_bounds__(256) void tconv_k(const float* __restrict__ W,
                                               bf* __restrict__ Wt, int K, int N)
{
  __shared__ float tile[64][65];
  const int t = threadIdx.x;
  const int bn = blockIdx.x * 64, bk = blockIdx.y * 64;
  const int r = t >> 2, c0 = (t & 3) * 16;
  #pragma unroll
  for (int i = 0; i < 4; ++i) {
    float4 f = *(const float4*)&W[(size_t)(bk + r) * N + bn + c0 + i * 4];
    tile[r][c0 + i*4 + 0] = f.x; tile[r][c0 + i*4 + 1] = f.y;
    tile[r][c0 + i*4 + 2] = f.z; tile[r][c0 + i*4 + 3] = f.w;
  }
  __syncthreads();
  #pragma unroll
  for (int i = 0; i < 4; ++i) {
    int c = c0 + i * 4;
    ushort4 u = make_ushort4(f2bf(tile[c + 0][r]), f2bf(tile[c + 1][r]),
                             f2bf(tile[c + 2][r]), f2bf(tile[c + 3][r]));
    *(ushort4*)&Wt[(size_t)(bn + r) * K + bk + c] = u;
  }
}

// ---- 3x [768][768] transpose-convert in one launch (z = which matrix) ----
__global__ __launch_bounds__(256) void tconv3_k(const float* __restrict__ Wq,
                                                const float* __restrict__ Wk,
                                                const float* __restrict__ Wv,
                                                bf* __restrict__ Wt)
{
  __shared__ float tile[64][65];
  const float* W = (blockIdx.z == 0) ? Wq : ((blockIdx.z == 1) ? Wk : Wv);
  bf* dst = Wt + (size_t)blockIdx.z * 589824;
  const int t = threadIdx.x;
  const int bn = blockIdx.x * 64, bk = blockIdx.y * 64;
  const int r = t >> 2, c0 = (t & 3) * 16;
  #pragma unroll
  for (int i = 0; i < 4; ++i) {
    float4 f = *(const float4*)&W[(size_t)(bk + r) * 768 + bn + c0 + i * 4];
    tile[r][c0 + i*4 + 0] = f.x; tile[r][c0 + i*4 + 1] = f.y;
    tile[r][c0 + i*4 + 2] = f.z; tile[r][c0 + i*4 + 3] = f.w;
  }
  __syncthreads();
  #pragma unroll
  for (int i = 0; i < 4; ++i) {
    int c = c0 + i * 4;
    ushort4 u = make_ushort4(f2bf(tile[c + 0][r]), f2bf(tile[c + 1][r]),
                             f2bf(tile[c + 2][r]), f2bf(tile[c + 3][r]));
    *(ushort4*)&dst[(size_t)(bn + r) * 768 + bk + c] = u;
  }
}

// ---- 2-phase pipelined GEMM with T2 swizzle (round-17 proven) ----
template <int BN, typename TC>
__global__ __launch_bounds__(256) void gl_gemm_k(
    const bf* __restrict__ A, const bf* __restrict__ Bt,
    const float* __restrict__ bias, TC* __restrict__ C,
    int M, int N, int K, int ldbt, int ep)
{
  constexpr int NJ = BN / 32;
  constexpr int ASZ = 16384;
  constexpr int BSZ = BN * 128;
  __shared__ char smem[2 * (ASZ + BSZ)];
  const int t = threadIdx.x;
  const int bm = blockIdx.y * 128, bn = blockIdx.x * BN;
  const int lane = t & 63, wid = t >> 6;
  const int wm = wid >> 1, wn = wid & 1;
  const int fr = lane & 15, fq = lane >> 4;
  const int lr = lane >> 3;
  const int lksw = (((lane & 7) ^ lr) << 3);  // pre-swizzled k-element offset

  f32x4 acc[4][NJ];
  #pragma unroll
  for (int i = 0; i < 4; ++i)
    #pragma unroll
    for (int j = 0; j < NJ; ++j) acc[i][j] = (f32x4){0.f, 0.f, 0.f, 0.f};

  auto STAGE = [&](int p, int k0) {
    char* sA = smem + p * (ASZ + BSZ);
    char* sB = sA + ASZ;
    #pragma unroll
    for (int c = 0; c < 4; ++c) {
      int chunk = wid * 4 + c;
      gload16(A + (size_t)(bm + chunk * 8 + lr) * K + k0 + lksw, sA + chunk * 1024);
    }
    #pragma unroll
    for (int c = 0; c < NJ; ++c) {
      int chunk = wid * NJ + c;
      gload16(Bt + (size_t)(bn + chunk * 8 + lr) * ldbt + k0 + lksw, sB + chunk * 1024);
    }
  };

  const int T = K >> 6;
  STAGE(0, 0);
  asm volatile("s_waitcnt vmcnt(0)" ::: "memory");
  __builtin_amdgcn_s_barrier();
  __builtin_amdgcn_sched_barrier(0);
  int cur = 0;
  for (int tt = 0; tt < T; ++tt) {
    if (tt + 1 < T) STAGE(cur ^ 1, (tt + 1) * 64);
    __builtin_amdgcn_sched_barrier(0);
    char* sA = smem + cur * (ASZ + BSZ);
    char* sB = sA + ASZ;
    __builtin_amdgcn_s_setprio(1);
    #pragma unroll
    for (int kk = 0; kk < 2; ++kk) {
      const int kb = kk * 64 + fq * 16;
      bf16x8 a[4], b[NJ];
      #pragma unroll
      for (int i = 0; i < 4; ++i) {
        int row = wm * 64 + i * 16 + fr;
        a[i] = *(const bf16x8*)(sA + row * 128 + (kb ^ ((row & 7) << 4)));
      }
      #pragma unroll
      for (int j = 0; j < NJ; ++j) {
        int col = wn * (BN / 2) + j * 16 + fr;
        b[j] = *(const bf16x8*)(sB + col * 128 + (kb ^ ((col & 7) << 4)));
      }
      #pragma unroll
      for (int i = 0; i < 4; ++i)
        #pragma unroll
        for (int j = 0; j < NJ; ++j)
          acc[i][j] = __builtin_amdgcn_mfma_f32_16x16x32_bf16(a[i], b[j], acc[i][j], 0, 0, 0);
    }
    __builtin_amdgcn_s_setprio(0);
    __builtin_amdgcn_sched_barrier(0);
    asm volatile("s_waitcnt vmcnt(0)" ::: "memory");
    __builtin_amdgcn_s_barrier();
    __builtin_amdgcn_sched_barrier(0);
    cur ^= 1;
  }
  #pragma unroll
  for (int j = 0; j < NJ; ++j) {
    int col = bn + wn * (BN / 2) + j * 16 + fr;
    float bias_v = bias ? bias[col] : 0.f;
    #pragma unroll
    for (int i = 0; i < 4; ++i) {
      int row0 = bm + wm * 64 + i * 16 + fq * 4;
      #pragma unroll
      for (int r = 0; r < 4; ++r) {
        float v = acc[i][j][r] + bias_v;
        if (ep == 1) v = 0.5f * v * (1.0f + erff(v * 0.70710678118654752f));
        if constexpr (sizeof(TC) == 2) C[(size_t)(row0 + r) * N + col] = f2bf(v);
        else                           C[(size_t)(row0 + r) * N + col] = v;
      }
    }
  }
}

// ---- QKV GEMM, same pipeline + swizzle; N=2304 over [Wq|Wk|Wv]^T ----
__global__ __launch_bounds__(256) void qkv_gl_k(
    const bf* __restrict__ A, const bf* __restrict__ Bt,
    const float* __restrict__ bq, const float* __restrict__ bk,
    const float* __restrict__ bv,
    bf* __restrict__ Qo, bf* __restrict__ Ko, bf* __restrict__ Vo)
{
  constexpr int ASZ = 16384, BSZ = 16384;
  __shared__ char smem[2 * (ASZ + BSZ)];
  const int t = threadIdx.x;
  const int bm = blockIdx.y * 128, bn = blockIdx.x * 128;
  const int lane = t & 63, wid = t >> 6;
  const int wm = wid >> 1, wn = wid & 1;
  const int fr = lane & 15, fq = lane >> 4;
  const int lr = lane >> 3;
  const int lksw = (((lane & 7) ^ lr) << 3);
  const int K = 768;

  f32x4 acc[4][4];
  #pragma unroll
  for (int i = 0; i < 4; ++i)
    #pragma unroll
    for (int j = 0; j < 4; ++j) acc[i][j] = (f32x4){0.f, 0.f, 0.f, 0.f};

  auto STAGE = [&](int p, int k0) {
    char* sA = smem + p * (ASZ + BSZ);
    char* sB = sA + ASZ;
    #pragma unroll
    for (int c = 0; c < 4; ++c) {
      int chunk = wid * 4 + c;
      gload16(A + (size_t)(bm + chunk * 8 + lr) * K + k0 + lksw, sA + chunk * 1024);
    }
    #pragma unroll
    for (int c = 0; c < 4; ++c) {
      int chunk = wid * 4 + c;
      gload16(Bt + (size_t)(bn + chunk * 8 + lr) * K + k0 + lksw, sB + chunk * 1024);
    }
  };

  STAGE(0, 0);
  asm volatile("s_waitcnt vmcnt(0)" ::: "memory");
  __builtin_amdgcn_s_barrier();
  __builtin_amdgcn_sched_barrier(0);
  int cur = 0;
  for (int tt = 0; tt < 12; ++tt) {
    if (tt + 1 < 12) STAGE(cur ^ 1, (tt + 1) * 64);
    __builtin_amdgcn_sched_barrier(0);
    char* sA = smem + cur * (ASZ + BSZ);
    char* sB = sA + ASZ;
    __builtin_amdgcn_s_setprio(1);
    #pragma unroll
    for (int kk = 0; kk < 2; ++kk) {
      const int kb = kk * 64 + fq * 16;
      bf16x8 a[4], b[4];
      #pragma unroll
      for (int i = 0; i < 4; ++i) {
        int row = wm * 64 + i * 16 + fr;
        a[i] = *(const bf16x8*)(sA + row * 128 + (kb ^ ((row & 7) << 4)));
      }
      #pragma unroll
      for (int j = 0; j < 4; ++j) {
        int col = wn * 64 + j * 16 + fr;
        b[j] = *(const bf16x8*)(sB + col * 128 + (kb ^ ((col & 7) << 4)));
      }
      #pragma unroll
      for (int i = 0; i < 4; ++i)
        #pragma unroll
        for (int j = 0; j < 4; ++j)
          acc[i][j] = __builtin_amdgcn_mfma_f32_16x16x32_bf16(a[i], b[j], acc[i][j], 0, 0, 0);
    }
    __builtin_amdgcn_s_setprio(0);
    __builtin_amdgcn_sched_barrier(0);
    asm volatile("s_waitcnt vmcnt(0)" ::: "memory");
    __builtin_amdgcn_s_barrier();
    __builtin_amdgcn_sched_barrier(0);
    cur ^= 1;
  }
  const int seg = bn / 768;
  const int cb  = bn - seg * 768;
  bf* dst = (seg == 0) ? Qo : ((seg == 1) ? Ko : Vo);
  const float* bias = (seg == 0) ? bq : ((seg == 1) ? bk : bv);
  #pragma unroll
  for (int j = 0; j < 4; ++j) {
    int col = cb + wn * 64 + j * 16 + fr;
    float bias_v = bias[col];
    #pragma unroll
    for (int i = 0; i < 4; ++i) {
      int row0 = bm + wm * 64 + i * 16 + fq * 4;
      #pragma unroll
      for (int r = 0; r < 4; ++r)
        dst[(size_t)(row0 + r) * 768 + col] = f2bf(acc[i][j][r] + bias_v);
    }
  }
}

// stage one prefetched K/V block into LDS buffers
__device__ __forceinline__ void stage_kv(char* bK, char* bVT,
    int kkey, int kd0, int vkey, int w,
    uint4 k0, uint4 k1, uint4 v0, uint4 v1)
{
  const int sw = (kkey & 7) << 4;
  *(uint4*)(bK + kkey * 128 + ((2 * kd0) ^ sw))      = k0;
  *(uint4*)(bK + kkey * 128 + ((2 * kd0 + 16) ^ sw)) = k1;
  union { uint4 q; unsigned short s[8]; } a, c;
  a.q = v0; c.q = v1;
  #pragma unroll
  for (int i = 0; i < 8; ++i) {
    int d = w * 16 + i;
    *(unsigned short*)(bVT + d * 128 + ((2 * vkey) ^ ((d & 7) << 4))) = a.s[i];
  }
  #pragma unroll
  for (int i = 0; i < 8; ++i) {
    int d = w * 16 + 8 + i;
    *(unsigned short*)(bVT + d * 128 + ((2 * vkey) ^ ((d & 7) << 4))) = c.s[i];
  }
}

// ---------------- BigBird attention v5 (round-15/17 proven) ----------------
__global__ __launch_bounds__(256) void attn5_kernel(
    const bf* __restrict__ Q, const bf* __restrict__ K,
    const bf* __restrict__ V, const int* __restrict__ rnd,
    float* __restrict__ ctx, float* __restrict__ part, int nseg)
{
  __shared__ char sQP[8192];
  __shared__ char sKV[2][16384];
  __shared__ int klist[8];
  const int t = threadIdx.x;
  const int lane = t & 63, w = t >> 6;
  const int fr = lane & 15, fq = lane >> 4;
  const int wg = blockIdx.x;
  const int nheavy = 48 * nseg;
  const bool heavy = wg < nheavy;
  int b, h, n, nkb, seg = 0, hidx = 0, segBase = 0;
  if (heavy) {
    hidx = wg / nseg; seg = wg - hidx * nseg;
    n = (hidx & 1) ? 63 : 0;
    int bh = hidx >> 1; h = bh % 12; b = bh / 12;
    nkb = 64 / nseg; segBase = seg * nkb;
  } else {
    int idx = wg - nheavy;
    n = 1 + (idx % 62);
    int bh = idx / 62; h = bh % 12; b = bh / 12;
    nkb = (n == 1 || n == 62) ? 7 : 8;
    if (t == 0) {
      int cnt = 0;
      if (n == 1)       { klist[0]=0; klist[1]=1;  klist[2]=2;  klist[3]=63; cnt=4; }
      else if (n == 62) { klist[0]=0; klist[1]=61; klist[2]=62; klist[3]=63; cnt=4; }
      else              { klist[0]=0; klist[1]=n-1; klist[2]=n; klist[3]=n+1; cnt=4; }
      for (int j = 0; j < 3; ++j) klist[cnt++] = rnd[(h * 62 + (n - 1)) * 3 + j];
      if (n != 1 && n != 62) klist[cnt++] = 63;
    }
  }
  const size_t qbase = ((size_t)b * 4096 + (size_t)n * 64) * 768 + h * 64;

  {
    int row = t >> 2, d0 = (t & 3) * 16;
    const bf* qp = &Q[qbase + (size_t)row * 768 + d0];
    #pragma unroll
    for (int i = 0; i < 2; ++i) {
      int off = row * 128 + ((2 * (d0 + 8 * i)) ^ ((row & 7) << 4));
      *(uint4*)(sQP + off) = *(const uint4*)(qp + 8 * i);
    }
  }
  __syncthreads();
  bf16x8 qf[2];
  {
    int row = w * 16 + fr;
    qf[0] = *(const bf16x8*)(sQP + row * 128 + ((2 * (fq * 8))      ^ ((row & 7) << 4)));
    qf[1] = *(const bf16x8*)(sQP + row * 128 + ((2 * (32 + fq * 8)) ^ ((row & 7) << 4)));
  }

  const int kkey = t >> 2, kd0 = (t & 3) * 16;
  const int vkey = lane;

  uint4 pk0, pk1, pv0, pv1;
  {
    int kb = heavy ? segBase : klist[0];
    size_t kbase = ((size_t)b * 4096 + (size_t)kb * 64) * 768 + h * 64;
    const bf* kp = &K[kbase + (size_t)kkey * 768 + kd0];
    pk0 = *(const uint4*)kp;  pk1 = *(const uint4*)(kp + 8);
    const bf* vp = &V[kbase + (size_t)vkey * 768 + w * 16];
    pv0 = *(const uint4*)vp;  pv1 = *(const uint4*)(vp + 8);
  }
  stage_kv(sKV[0], sKV[0] + 8192, kkey, kd0, vkey, w, pk0, pk1, pv0, pv1);

  float m_r[4] = {-1e30f, -1e30f, -1e30f, -1e30f};
  float l_r[4] = {0.f, 0.f, 0.f, 0.f};
  f32x4 acc_o[4];
  #pragma unroll
  for (int j = 0; j < 4; ++j) acc_o[j] = (f32x4){0.f, 0.f, 0.f, 0.f};

  for (int ib = 0; ib < nkb; ++ib) {
    char* bK  = sKV[ib & 1];
    char* bVT = bK + 8192;
    const bool pfv = (ib + 1 < nkb);
    if (pfv) {
      int kb = heavy ? (segBase + ib + 1) : klist[ib + 1];
      size_t kbase = ((size_t)b * 4096 + (size_t)kb * 64) * 768 + h * 64;
      const bf* kp = &K[kbase + (size_t)kkey * 768 + kd0];
      pk0 = *(const uint4*)kp;  pk1 = *(const uint4*)(kp + 8);
      const bf* vp = &V[kbase + (size_t)vkey * 768 + w * 16];
      pv0 = *(const uint4*)vp;  pv1 = *(const uint4*)(vp + 8);
    }
    __syncthreads();
    f32x4 s4[4];
    #pragma unroll
    for (int j = 0; j < 4; ++j) s4[j] = (f32x4){0.f, 0.f, 0.f, 0.f};
    __builtin_amdgcn_s_setprio(1);
    #pragma unroll
    for (int kk = 0; kk < 2; ++kk) {
      #pragma unroll
      for (int j = 0; j < 4; ++j) {
        int key = j * 16 + fr;
        bf16x8 kf = *(const bf16x8*)(bK + key * 128 + ((2 * (kk * 32 + fq * 8)) ^ ((key & 7) << 4)));
        s4[j] = __builtin_amdgcn_mfma_f32_16x16x32_bf16(qf[kk], kf, s4[j], 0, 0, 0);
      }
    }
    __builtin_amdgcn_s_setprio(0);
    #pragma unroll
    for (int j = 0; j < 4; ++j) s4[j] *= 0.125f;
    float c_r[4];
    #pragma unroll
    for (int r = 0; r < 4; ++r) {
      float mx = fmaxf(fmaxf(s4[0][r], s4[1][r]), fmaxf(s4[2][r], s4[3][r]));
      #pragma unroll
      for (int m = 1; m < 16; m <<= 1) mx = fmaxf(mx, __shfl_xor(mx, m, 64));
      float mn = fmaxf(mx, m_r[r]);
      float c  = __expf(m_r[r] - mn);
      float p0 = __expf(s4[0][r] - mn), p1 = __expf(s4[1][r] - mn);
      float p2 = __expf(s4[2][r] - mn), p3 = __expf(s4[3][r] - mn);
      s4[0][r] = p0; s4[1][r] = p1; s4[2][r] = p2; s4[3][r] = p3;
      float sum = p0 + p1 + p2 + p3;
      #pragma unroll
      for (int m = 1; m < 16; m <<= 1) sum += __shfl_xor(sum, m, 64);
      l_r[r] = l_r[r] * c + sum;
      m_r[r] = mn;
      c_r[r] = c;
    }
    #pragma unroll
    for (int j = 0; j < 4; ++j)
      #pragma unroll
      for (int r = 0; r < 4; ++r) acc_o[j][r] *= c_r[r];
    #pragma unroll
    for (int r = 0; r < 4; ++r) {
      int prow = w * 16 + fq * 4 + r;
      int rs = prow * 128, sw = (prow & 7) << 4;
      #pragma unroll
      for (int j = 0; j < 4; ++j)
        *(unsigned short*)(sQP + rs + ((2 * (j * 16 + fr)) ^ sw)) = f2bf(s4[j][r]);
    }
    if (pfv)
      stage_kv(sKV[(ib & 1) ^ 1], sKV[(ib & 1) ^ 1] + 8192, kkey, kd0, vkey, w,
               pk0, pk1, pv0, pv1);
    __builtin_amdgcn_s_setprio(1);
    #pragma unroll
    for (int kk = 0; kk < 2; ++kk) {
      int prow = w * 16 + fr;
      bf16x8 pf8 = *(const bf16x8*)(sQP + prow * 128 + ((2 * (kk * 32 + fq * 8)) ^ ((prow & 7) << 4)));
      #pragma unroll
      for (int j = 0; j < 4; ++j) {
        int col = j * 16 + fr;
        bf16x8 vf = *(const bf16x8*)(bVT + col * 128 + ((2 * (kk * 32 + fq * 8)) ^ ((col & 7) << 4)));
        acc_o[j] = __builtin_amdgcn_mfma_f32_16x16x32_bf16(pf8, vf, acc_o[j], 0, 0, 0);
      }
    }
    __builtin_amdgcn_s_setprio(0);
  }
  if (heavy && nseg > 1) {
    float* pb = part + ((size_t)hidx * nseg + seg) * 4224;
    int row0 = w * 16 + fq * 4;
    #pragma unroll
    for (int r = 0; r < 4; ++r) {
      int row = row0 + r;
      if (fr == 0) { pb[4096 + row] = m_r[r]; pb[4160 + row] = l_r[r]; }
      #pragma unroll
      for (int j = 0; j < 4; ++j)
        pb[row * 64 + j * 16 + fr] = acc_o[j][r];
    }
  } else {
    int row0 = w * 16 + fq * 4;
    #pragma unroll
    for (int r = 0; r < 4; ++r) {
      float inv = 1.f / l_r[r];
      size_t rowoff = qbase + (size_t)(row0 + r) * 768;
      #pragma unroll
      for (int j = 0; j < 4; ++j)
        ctx[rowoff + j * 16 + fr] = acc_o[j][r] * inv;
    }
  }
}

// ---- combine partials for heavy blocks (nseg=8) ----
__global__ __launch_bounds__(256) void attn_combine_k(
    const float* __restrict__ part, float* __restrict__ ctx)
{
  const int hidx = blockIdx.x;
  const int t = threadIdx.x;
  const int n = (hidx & 1) ? 63 : 0;
  const int bh = hidx >> 1;
  const int h = bh % 12, b = bh / 12;
  const size_t qbase = ((size_t)b * 4096 + (size_t)n * 64) * 768 + h * 64;
  const int r = t >> 2, d0 = (t & 3) * 16;
  const float* pb = part + (size_t)hidx * 8 * 4224;
  float mi[8], li[8], m = -1e30f;
  #pragma unroll
  for (int i = 0; i < 8; ++i) {
    mi[i] = pb[i * 4224 + 4096 + r];
    li[i] = pb[i * 4224 + 4160 + r];
    m = fmaxf(m, mi[i]);
  }
  float w8[8], L = 0.f;
  #pragma unroll
  for (int i = 0; i < 8; ++i) { w8[i] = __expf(mi[i] - m); L += li[i] * w8[i]; }
  float inv = 1.f / L;
  #pragma unroll
  for (int dd = 0; dd < 4; ++dd) {
    int d = d0 + dd * 4;
    float4 o = {0.f, 0.f, 0.f, 0.f};
    #pragma unroll
    for (int i = 0; i < 8; ++i) {
      float4 p = *(const float4*)&pb[i * 4224 + r * 64 + d];
      o.x = fmaf(w8[i], p.x, o.x); o.y = fmaf(w8[i], p.y, o.y);
      o.z = fmaf(w8[i], p.z, o.z); o.w = fmaf(w8[i], p.w, o.w);
    }
    o.x *= inv; o.y *= inv; o.z *= inv; o.w *= inv;
    *(float4*)&ctx[qbase + (size_t)r * 768 + d] = o;
  }
}

// ---------------- LayerNorm(a + res) * g + b ----------------
template <typename TR, typename TO>
__global__ __launch_bounds__(256) void ln_kernel(
    const float* __restrict__ a, const TR* __restrict__ res,
    const float* __restrict__ g, const float* __restrict__ bb,
    TO* __restrict__ out)
{
  const int row = blockIdx.x, t = threadIdx.x;
  __shared__ float buf[768];
  __shared__ float rs[4], rss[4];
  const size_t base = (size_t)row * 768;
  float s = 0.f, ss = 0.f;
  for (int c = t; c < 768; c += 256) {
    float rv;
    if constexpr (sizeof(TR) == 2) rv = bf2f(res[base + c]);
    else                           rv = res[base + c];
    float v = a[base + c] + rv;
    buf[c] = v;
    s += v;
    ss = fmaf(v, v, ss);
  }
  #pragma unroll
  for (int off = 32; off > 0; off >>= 1) {
    s  += __shfl_down(s, off, 64);
    ss += __shfl_down(ss, off, 64);
  }
  if ((t & 63) == 0) { rs[t >> 6] = s; rss[t >> 6] = ss; }
  __syncthreads();
  float S  = rs[0] + rs[1] + rs[2] + rs[3];
  float SS = rss[0] + rss[1] + rss[2] + rss[3];
  float mu  = S * (1.f / 768.f);
  float var = SS * (1.f / 768.f) - mu * mu;
  float inv = rsqrtf(var + 1e-5f);
  for (int c = t; c < 768; c += 256) {
    float v = (buf[c] - mu) * inv * g[c] + bb[c];
    if constexpr (sizeof(TO) == 2) out[base + c] = f2bf(v);
    else                           out[base + c] = v;
  }
}

extern "C" void kernel_launch(void* const* d_in, const int* in_sizes, int n_in,
                              void* d_out, int out_size, void* d_ws, size_t ws_size,
                              hipStream_t stream)
{
  const float* x   = (const float*)d_in[0];
  const int*   rnd = (const int*)d_in[1];
  const float* Wq  = (const float*)d_in[2];
  const float* bq  = (const float*)d_in[3];
  const float* Wk  = (const float*)d_in[4];
  const float* bk  = (const float*)d_in[5];
  const float* Wv  = (const float*)d_in[6];
  const float* bv  = (const float*)d_in[7];
  const float* g1  = (const float*)d_in[8];
  const float* be1 = (const float*)d_in[9];
  const float* W1  = (const float*)d_in[10];
  const float* b1  = (const float*)d_in[11];
  const float* W2  = (const float*)d_in[12];
  const float* b2  = (const float*)d_in[13];
  const float* g2  = (const float*)d_in[14];
  const float* be2 = (const float*)d_in[15];
  float* out = (float*)d_out;

  char* W = (char*)d_ws;
  bf* w1t   = (bf*)(W);                 // [3072][768]
  bf* w2t   = (bf*)(W + 4718592);       // [768][3072]
  bf* Kb    = (bf*)(W + 9437184);       // [8192][768], h1 later
  bf* wqkv  = (bf*)(W + 22020096);      // [2304][768]
  bf* xb    = (bf*)(W + 25559040);      // [8192][768]
  bf* Qb    = (bf*)(W + 38141952);      // [8192][768]
  bf* Vb    = (bf*)(W + 50724864);      // [8192][768]
  float* part = (float*)(W + 63307776); // 48*8*4224 f32
  bf* f1    = (bf*)(W + 22020096);      // [8192][3072], overlays dead buffers
  bf* h1    = Kb;
  float* ctx = out;
  float* f2  = out;

  dim3 blk(256);
  cvt_x_k<<<dim3(3072), blk, 0, stream>>>(x, xb);
  tconv3_k<<<dim3(12, 12, 3), blk, 0, stream>>>(Wq, Wk, Wv, wqkv);
  tconv_k<<<dim3(48, 12), blk, 0, stream>>>(W1, w1t,  768, 3072);
  tconv_k<<<dim3(12, 48), blk, 0, stream>>>(W2, w2t, 3072,  768);
  qkv_gl_k<<<dim3(18, 64), blk, 0, stream>>>(xb, wqkv, bq, bk, bv, Qb, Kb, Vb);
  attn5_kernel<<<dim3(48 * 8 + 2 * 12 * 62), blk, 0, stream>>>(
      Qb, Kb, Vb, rnd, ctx, part, 8);
  attn_combine_k<<<dim3(48), blk, 0, stream>>>(part, ctx);
  ln_kernel<float, bf><<<dim3(8192), blk, 0, stream>>>(ctx, x, g1, be1, h1);
  gl_gemm_k<128, bf><<<dim3(24, 64), blk, 0, stream>>>(
      h1, w1t, b1, f1, 8192, 3072, 768, 768, 1);
  gl_gemm_k<128, float><<<dim3(6, 64), blk, 0, stream>>>(
      f1, w2t, b2, f2, 8192, 768, 3072, 3072, 0);
  ln_kernel<bf, float><<<dim3(8192), blk, 0, stream>>>(f2, h1, g2, be2, out);
}